// Round 1
// baseline (627.739 us; speedup 1.0000x reference)
//
#include <hip/hip_runtime.h>
#include <hip/hip_bf16.h>

typedef __attribute__((ext_vector_type(8))) short short8;
typedef __attribute__((ext_vector_type(4))) float f32x4;

#define D 256
#define MT 64          // nodes per block in main kernel
#define LDA_PAD 264    // 256 + 8 bf16 pad -> uniform bank spread for ds_read_b128
#define G 8            // graphs per block in feat_v kernel

__device__ __forceinline__ unsigned short f2bf(float f) {
    unsigned int u = __float_as_uint(f);
    u += 0x7FFFu + ((u >> 16) & 1u);   // round-to-nearest-even
    return (unsigned short)(u >> 16);
}

// K0: convert W_u fp32 -> bf16 (row-major [j][k], which is exactly the
// B[k][j] = W_u[j][k] layout the MFMA B-fragment wants contiguous in k)
__global__ void k_convert(const float* __restrict__ W, unsigned short* __restrict__ Wb, int n) {
    int i = blockIdx.x * 256 + threadIdx.x;
    if (i < n) Wb[i] = f2bf(W[i]);
}

// K1: feat_v[b][j] = feat[last_nodes[b]] . W_v[j] + b_v[j]
__global__ __launch_bounds__(256) void k_featv(
    const float* __restrict__ feat, const int* __restrict__ last_nodes,
    const float* __restrict__ Wv, const float* __restrict__ bv,
    float* __restrict__ featv, int Bseg) {
    __shared__ float fln[G][D];
    const int t  = threadIdx.x;
    const int b0 = blockIdx.x * G;
    for (int g = 0; g < G; ++g) {
        int b = b0 + g;
        int ln = (b < Bseg) ? last_nodes[b] : 0;
        fln[g][t] = feat[(long)ln * D + t];
    }
    __syncthreads();
    float acc[G];
    float bvj = bv[t];
    #pragma unroll
    for (int g = 0; g < G; ++g) acc[g] = bvj;
    const float* wr = Wv + (long)t * D;
    for (int k = 0; k < D; k += 4) {
        float4 w4 = *(const float4*)(wr + k);
        #pragma unroll
        for (int g = 0; g < G; ++g) {
            acc[g] += w4.x * fln[g][k]     + w4.y * fln[g][k + 1]
                    + w4.z * fln[g][k + 2] + w4.w * fln[g][k + 3];
        }
    }
    for (int g = 0; g < G; ++g)
        if (b0 + g < Bseg) featv[(long)(b0 + g) * D + t] = acc[g];
}

// K2: fused  feat_u = feat@W_u^T  ->  e = sigmoid(u+v).w_e  ->  alpha = e*cnt
//      ->  segment_sum(feat * alpha)  via per-block atomics (segments sorted)
__global__ __launch_bounds__(256) void k_main(
    const float* __restrict__ feat, const float* __restrict__ cnt,
    const int* __restrict__ seg, const unsigned short* __restrict__ Wub,
    const float* __restrict__ featv, const float* __restrict__ we,
    float* __restrict__ rst, int N) {

    __shared__ unsigned short A_lds[MT * LDA_PAD];
    __shared__ float e_lds[4][MT];
    __shared__ int   seg_lds[MT];
    __shared__ float cnt_lds[MT];
    __shared__ float alpha_lds[MT];

    const int t  = threadIdx.x;
    const int n0 = blockIdx.x * MT;

    if (t < MT) {
        int n = n0 + t;
        seg_lds[t] = (n < N) ? seg[n] : 0;
        cnt_lds[t] = (n < N) ? cnt[n] : 0.f;
    }

    // stage feat tile [64][256] as bf16 into padded LDS
    #pragma unroll
    for (int it = 0; it < 16; ++it) {
        int f   = it * 256 + t;      // float4 index within tile (64 rows x 64 float4)
        int row = f >> 6;
        int c4  = f & 63;
        int n   = n0 + row;
        float4 v;
        if (n < N) v = *(const float4*)(feat + (long)n * D + c4 * 4);
        else       { v.x = v.y = v.z = v.w = 0.f; }
        unsigned int lo = (unsigned int)f2bf(v.x) | ((unsigned int)f2bf(v.y) << 16);
        unsigned int hi = (unsigned int)f2bf(v.z) | ((unsigned int)f2bf(v.w) << 16);
        *(uint2*)&A_lds[row * LDA_PAD + c4 * 4] = make_uint2(lo, hi);
    }
    __syncthreads();

    const int w  = t >> 6;   // wave id: j-range [64w, 64w+64)
    const int l  = t & 63;
    const int rl = l & 15;
    const int h  = l >> 4;

    f32x4 acc[4][4];
    #pragma unroll
    for (int mt = 0; mt < 4; ++mt)
        #pragma unroll
        for (int nt = 0; nt < 4; ++nt) acc[mt][nt] = (f32x4)0.f;

    // B fragments straight from L2-resident bf16 W_u
    const unsigned short* bbase = Wub + (long)(w * 64 + rl) * D + h * 8;

    #pragma unroll
    for (int s = 0; s < 8; ++s) {
        short8 a[4], b[4];
        #pragma unroll
        for (int mt = 0; mt < 4; ++mt)
            a[mt] = *(const short8*)&A_lds[(mt * 16 + rl) * LDA_PAD + s * 32 + h * 8];
        #pragma unroll
        for (int nt = 0; nt < 4; ++nt)
            b[nt] = *(const short8*)(bbase + nt * 16 * D + s * 32);
        #pragma unroll
        for (int mt = 0; mt < 4; ++mt)
            #pragma unroll
            for (int nt = 0; nt < 4; ++nt)
                acc[mt][nt] = __builtin_amdgcn_mfma_f32_16x16x32_bf16(a[mt], b[nt], acc[mt][nt], 0, 0, 0);
    }

    // epilogue: e partials  (D row = 16mt + 4h + r, col j = 64w + 16nt + rl)
    float wev[4];
    #pragma unroll
    for (int nt = 0; nt < 4; ++nt) wev[nt] = we[w * 64 + nt * 16 + rl];

    float ep[4][4];
    #pragma unroll
    for (int mt = 0; mt < 4; ++mt)
        #pragma unroll
        for (int r = 0; r < 4; ++r) {
            int rowl = mt * 16 + h * 4 + r;
            int sg = seg_lds[rowl];
            const float* fv = featv + (long)sg * D + w * 64 + rl;
            float s = 0.f;
            #pragma unroll
            for (int nt = 0; nt < 4; ++nt) {
                float x = acc[mt][nt][r] + fv[nt * 16];
                s += wev[nt] / (1.f + __expf(-x));
            }
            ep[mt][r] = s;
        }

    // reduce across the 16 lanes sharing h (cols of this wave)
    #pragma unroll
    for (int m = 1; m < 16; m <<= 1) {
        #pragma unroll
        for (int mt = 0; mt < 4; ++mt)
            #pragma unroll
            for (int r = 0; r < 4; ++r)
                ep[mt][r] += __shfl_xor(ep[mt][r], m, 16);
    }
    if (rl == 0) {
        #pragma unroll
        for (int mt = 0; mt < 4; ++mt)
            #pragma unroll
            for (int r = 0; r < 4; ++r)
                e_lds[w][mt * 16 + h * 4 + r] = ep[mt][r];
    }
    __syncthreads();

    if (t < MT) {
        float e = e_lds[0][t] + e_lds[1][t] + e_lds[2][t] + e_lds[3][t];
        alpha_lds[t] = e * cnt_lds[t];
    }
    __syncthreads();

    // fused segment sum: thread t owns dim d = t; nodes are sorted by segment
    {
        int nvalid = min(MT, N - n0);
        float c = 0.f;
        int cur = seg_lds[0];
        for (int i = 0; i < nvalid; ++i) {
            int sgi = seg_lds[i];
            if (sgi != cur) { atomicAdd(&rst[(long)cur * D + t], c); c = 0.f; cur = sgi; }
            c += feat[(long)(n0 + i) * D + t] * alpha_lds[i];
        }
        atomicAdd(&rst[(long)cur * D + t], c);
    }
}

extern "C" void kernel_launch(void* const* d_in, const int* in_sizes, int n_in,
                              void* d_out, int out_size, void* d_ws, size_t ws_size,
                              hipStream_t stream) {
    const float* feat = (const float*)d_in[0];
    const float* cnt  = (const float*)d_in[1];
    const int*   seg  = (const int*)d_in[2];
    const int*   last = (const int*)d_in[3];
    const float* Wu   = (const float*)d_in[4];
    const float* Wv   = (const float*)d_in[5];
    const float* bv   = (const float*)d_in[6];
    const float* we   = (const float*)d_in[7];
    float* rst = (float*)d_out;

    const int N    = in_sizes[1];  // cnt is [N]
    const int Bseg = in_sizes[3];  // last_nodes is [B]

    unsigned short* Wub   = (unsigned short*)d_ws;
    float*          featv = (float*)((char*)d_ws + (size_t)D * D * sizeof(unsigned short));

    hipMemsetAsync(d_out, 0, (size_t)out_size * sizeof(float), stream);
    k_convert<<<(D * D + 255) / 256, 256, 0, stream>>>(Wu, Wub, D * D);
    k_featv<<<(Bseg + G - 1) / G, 256, 0, stream>>>(feat, last, Wv, bv, featv, Bseg);
    k_main<<<(N + MT - 1) / MT, 256, 0, stream>>>(feat, cnt, seg, Wub, featv, we, rst, N);
}

// Round 2
// 481.492 us; speedup vs baseline: 1.3037x; 1.3037x over previous
//
#include <hip/hip_runtime.h>
#include <hip/hip_bf16.h>

typedef __attribute__((ext_vector_type(8))) short short8;
typedef __attribute__((ext_vector_type(4))) float f32x4;

#define D 256
#define MT 64          // nodes per tile
#define LDW 264        // LDS row stride (bf16 elems): 256 + 8 pad
#define GRID_MAIN 512
#define G 8            // graphs per block in feat_v kernel

__device__ __forceinline__ unsigned short f2bf(float f) {
    unsigned int u = __float_as_uint(f);
    u += 0x7FFFu + ((u >> 16) & 1u);   // RTNE
    return (unsigned short)(u >> 16);
}
__device__ __forceinline__ float bf2f(unsigned short s) {
    return __uint_as_float(((unsigned int)s) << 16);
}
__device__ __forceinline__ float fast_sigmoid(float x) {
    return __builtin_amdgcn_rcpf(1.f + __expf(-x));
}

// K0: W_u fp32 -> bf16 row-major
__global__ void k_convert(const float* __restrict__ W, unsigned short* __restrict__ Wb, int n) {
    int i = blockIdx.x * 256 + threadIdx.x;
    if (i < n) Wb[i] = f2bf(W[i]);
}

// K1: feat_v[b] = feat[last_nodes[b]] @ W_v.T + b_v
__global__ __launch_bounds__(256) void k_featv(
    const float* __restrict__ feat, const int* __restrict__ last_nodes,
    const float* __restrict__ Wv, const float* __restrict__ bv,
    float* __restrict__ featv, int Bseg) {
    __shared__ float fln[G][D];
    const int t  = threadIdx.x;
    const int b0 = blockIdx.x * G;
    for (int g = 0; g < G; ++g) {
        int b = b0 + g;
        int ln = (b < Bseg) ? last_nodes[b] : 0;
        fln[g][t] = feat[(long)ln * D + t];
    }
    __syncthreads();
    float acc[G];
    float bvj = bv[t];
    #pragma unroll
    for (int g = 0; g < G; ++g) acc[g] = bvj;
    const float* wr = Wv + (long)t * D;
    for (int k = 0; k < D; k += 4) {
        float4 w4 = *(const float4*)(wr + k);
        #pragma unroll
        for (int g = 0; g < G; ++g) {
            acc[g] += w4.x * fln[g][k]     + w4.y * fln[g][k + 1]
                    + w4.z * fln[g][k + 2] + w4.w * fln[g][k + 3];
        }
    }
    for (int g = 0; g < G; ++g)
        if (b0 + g < Bseg) featv[(long)(b0 + g) * D + t] = acc[g];
}

// K2: persistent fused kernel.
//   u = W_u @ feat_tile^T  (out [j][node]) via MFMA
//   e = w_e . sigmoid(u + featv[seg])  (lane-local j-reduce)
//   alpha = e * cnt ; segment_sum(feat*alpha) from LDS bf16 tile
__global__ __launch_bounds__(256, 2) void k_main(
    const float* __restrict__ feat, const float* __restrict__ cnt,
    const int* __restrict__ seg, const unsigned short* __restrict__ Wub,
    const float* __restrict__ featv, const float* __restrict__ we,
    float* __restrict__ rst, int N) {

    __shared__ unsigned short A_lds[MT * LDW];
    __shared__ float e_lds[4][MT];
    __shared__ int   seg_lds[MT];
    __shared__ float cnt_lds[MT];
    __shared__ float alpha_lds[MT];

    const int t  = threadIdx.x;
    const int w  = t >> 6;
    const int l  = t & 63;
    const int rl = l & 15;
    const int h  = l >> 4;

    // balanced contiguous chunk of tiles for this block
    const int T   = (N + MT - 1) / MT;
    const int nb  = gridDim.x;
    const int per = T / nb, rem = T % nb;
    const int bid = blockIdx.x;
    const int c0  = bid * per + (bid < rem ? bid : rem);
    const int c1  = c0 + per + (bid < rem ? 1 : 0);
    if (c0 >= c1) return;

    // hoisted w_e fragments: lane needs we[64w + 16mt + 4h + r]
    f32x4 wev[4];
    #pragma unroll
    for (int mt = 0; mt < 4; ++mt)
        wev[mt] = *(const f32x4*)(we + w * 64 + mt * 16 + h * 4);

    // ---- prologue: stage tile c0 ----
    {
        const int n0 = c0 * MT;
        float4 p0[8], p1[8];
        #pragma unroll
        for (int it = 0; it < 8; ++it) {
            int p = it * 256 + t, row = p >> 5, cu = p & 31;
            long n = (long)n0 + row;
            if (n < N) {
                p0[it] = *(const float4*)(feat + n * D + cu * 8);
                p1[it] = *(const float4*)(feat + n * D + cu * 8 + 4);
            } else {
                p0[it] = make_float4(0.f, 0.f, 0.f, 0.f);
                p1[it] = make_float4(0.f, 0.f, 0.f, 0.f);
            }
        }
        int sr = 0; float cr = 0.f;
        if (t < MT) {
            long n = (long)n0 + t;
            if (n < N) { sr = seg[n]; cr = cnt[n]; }
        }
        #pragma unroll
        for (int it = 0; it < 8; ++it) {
            int p = it * 256 + t, row = p >> 5, cu = p & 31;
            short8 v;
            v[0] = (short)f2bf(p0[it].x); v[1] = (short)f2bf(p0[it].y);
            v[2] = (short)f2bf(p0[it].z); v[3] = (short)f2bf(p0[it].w);
            v[4] = (short)f2bf(p1[it].x); v[5] = (short)f2bf(p1[it].y);
            v[6] = (short)f2bf(p1[it].z); v[7] = (short)f2bf(p1[it].w);
            *(short8*)&A_lds[row * LDW + cu * 8] = v;
        }
        if (t < MT) { seg_lds[t] = sr; cnt_lds[t] = cr; }
        __syncthreads();
    }

    for (int tt = c0; tt < c1; ++tt) {
        const int n0 = tt * MT;
        const bool more = (tt + 1 < c1);

        // P0: issue next tile's loads early (consumed in P5)
        float4 p0[8], p1[8];
        int sr = 0; float cr = 0.f;
        if (more) {
            const int m0 = (tt + 1) * MT;
            #pragma unroll
            for (int it = 0; it < 8; ++it) {
                int p = it * 256 + t, row = p >> 5, cu = p & 31;
                long n = (long)m0 + row;
                if (n < N) {
                    p0[it] = *(const float4*)(feat + n * D + cu * 8);
                    p1[it] = *(const float4*)(feat + n * D + cu * 8 + 4);
                } else {
                    p0[it] = make_float4(0.f, 0.f, 0.f, 0.f);
                    p1[it] = make_float4(0.f, 0.f, 0.f, 0.f);
                }
            }
            if (t < MT) {
                long n = (long)m0 + t;
                if (n < N) { sr = seg[n]; cr = cnt[n]; }
            }
        }

        // P1: u[j][node] MFMA.  A = W_u rows (global, L2-hot), B = feat tile (LDS)
        f32x4 acc[4][4];   // [mt][nt]
        #pragma unroll
        for (int mt = 0; mt < 4; ++mt)
            #pragma unroll
            for (int nt = 0; nt < 4; ++nt) acc[mt][nt] = (f32x4)0.f;

        const unsigned short* abase = Wub + (long)(w * 64 + rl) * D + h * 8;
        #pragma unroll
        for (int s = 0; s < 8; ++s) {
            short8 a[4], b[4];
            #pragma unroll
            for (int mt = 0; mt < 4; ++mt)
                a[mt] = *(const short8*)(abase + (long)mt * 16 * D + s * 32);
            #pragma unroll
            for (int nt = 0; nt < 4; ++nt)
                b[nt] = *(const short8*)&A_lds[(nt * 16 + rl) * LDW + s * 32 + h * 8];
            #pragma unroll
            for (int mt = 0; mt < 4; ++mt)
                #pragma unroll
                for (int nt = 0; nt < 4; ++nt)
                    acc[mt][nt] = __builtin_amdgcn_mfma_f32_16x16x32_bf16(a[mt], b[nt], acc[mt][nt], 0, 0, 0);
        }

        // P2: e partials.  lane's j = 64w + 16mt + 4h + r ; node = 16nt + rl
        float ep[4] = {0.f, 0.f, 0.f, 0.f};
        bool uni = (seg_lds[0] == seg_lds[MT - 1]);
        if (uni) {
            const float* fvb = featv + (long)seg_lds[0] * D + w * 64 + h * 4;
            #pragma unroll
            for (int mt = 0; mt < 4; ++mt) {
                f32x4 fv = *(const f32x4*)(fvb + mt * 16);
                #pragma unroll
                for (int r = 0; r < 4; ++r) {
                    float wv = wev[mt][r];
                    #pragma unroll
                    for (int nt = 0; nt < 4; ++nt)
                        ep[nt] += wv * fast_sigmoid(acc[mt][nt][r] + fv[r]);
                }
            }
        } else {
            #pragma unroll
            for (int nt = 0; nt < 4; ++nt) {
                int sg = seg_lds[nt * 16 + rl];
                const float* fvb = featv + (long)sg * D + w * 64 + h * 4;
                #pragma unroll
                for (int mt = 0; mt < 4; ++mt) {
                    f32x4 fv = *(const f32x4*)(fvb + mt * 16);
                    #pragma unroll
                    for (int r = 0; r < 4; ++r)
                        ep[nt] += wev[mt][r] * fast_sigmoid(acc[mt][nt][r] + fv[r]);
                }
            }
        }
        #pragma unroll
        for (int nt = 0; nt < 4; ++nt) {
            ep[nt] += __shfl_xor(ep[nt], 16);
            ep[nt] += __shfl_xor(ep[nt], 32);
        }
        if (h == 0) {
            #pragma unroll
            for (int nt = 0; nt < 4; ++nt) e_lds[w][nt * 16 + rl] = ep[nt];
        }
        __syncthreads();

        // P3: alpha
        if (t < MT) {
            float e = e_lds[0][t] + e_lds[1][t] + e_lds[2][t] + e_lds[3][t];
            alpha_lds[t] = e * cnt_lds[t];
        }
        __syncthreads();

        // P4: segment-sum from LDS bf16 tile; thread t owns dim d = t
        {
            int nv = N - n0; if (nv > MT) nv = MT;
            float c = 0.f;
            int cur = seg_lds[0];
            for (int i = 0; i < nv; ++i) {
                int sgi = seg_lds[i];                 // wave-uniform branch
                if (sgi != cur) {
                    atomicAdd(&rst[(long)cur * D + t], c);
                    c = 0.f; cur = sgi;
                }
                c += bf2f(A_lds[i * LDW + t]) * alpha_lds[i];
            }
            atomicAdd(&rst[(long)cur * D + t], c);
        }
        __syncthreads();

        // P5: write prefetched tile into LDS (vmcnt wait lands here, late)
        if (more) {
            #pragma unroll
            for (int it = 0; it < 8; ++it) {
                int p = it * 256 + t, row = p >> 5, cu = p & 31;
                short8 v;
                v[0] = (short)f2bf(p0[it].x); v[1] = (short)f2bf(p0[it].y);
                v[2] = (short)f2bf(p0[it].z); v[3] = (short)f2bf(p0[it].w);
                v[4] = (short)f2bf(p1[it].x); v[5] = (short)f2bf(p1[it].y);
                v[6] = (short)f2bf(p1[it].z); v[7] = (short)f2bf(p1[it].w);
                *(short8*)&A_lds[row * LDW + cu * 8] = v;
            }
            if (t < MT) { seg_lds[t] = sr; cnt_lds[t] = cr; }
            __syncthreads();
        }
    }
}

extern "C" void kernel_launch(void* const* d_in, const int* in_sizes, int n_in,
                              void* d_out, int out_size, void* d_ws, size_t ws_size,
                              hipStream_t stream) {
    const float* feat = (const float*)d_in[0];
    const float* cnt  = (const float*)d_in[1];
    const int*   seg  = (const int*)d_in[2];
    const int*   last = (const int*)d_in[3];
    const float* Wu   = (const float*)d_in[4];
    const float* Wv   = (const float*)d_in[5];
    const float* bv   = (const float*)d_in[6];
    const float* we   = (const float*)d_in[7];
    float* rst = (float*)d_out;

    const int N    = in_sizes[1];  // cnt is [N]
    const int Bseg = in_sizes[3];  // last_nodes is [B]

    unsigned short* Wub   = (unsigned short*)d_ws;
    float*          featv = (float*)((char*)d_ws + (size_t)D * D * sizeof(unsigned short));

    hipMemsetAsync(d_out, 0, (size_t)out_size * sizeof(float), stream);
    k_convert<<<(D * D + 255) / 256, 256, 0, stream>>>(Wu, Wub, D * D);
    k_featv<<<(Bseg + G - 1) / G, 256, 0, stream>>>(feat, last, Wv, bv, featv, Bseg);
    k_main<<<GRID_MAIN, 256, 0, stream>>>(feat, cnt, seg, Wub, featv, we, rst, N);
}

// Round 3
// 236.878 us; speedup vs baseline: 2.6501x; 2.0327x over previous
//
#include <hip/hip_runtime.h>
#include <hip/hip_bf16.h>

typedef __attribute__((ext_vector_type(8))) short short8;
typedef __attribute__((ext_vector_type(4))) float f32x4;

#define D 256
#define MT 64
#define NW 8             // waves per block (512 threads)
#define GRID_MAIN 256
#define CMAX 32          // max tiles per block (grid sized so this holds)
#define G 8

__device__ __forceinline__ unsigned short f2bf(float f) {
    unsigned int u = __float_as_uint(f);
    u += 0x7FFFu + ((u >> 16) & 1u);   // RTNE
    return (unsigned short)(u >> 16);
}
// pack two fp32 -> two bf16 (truncation) in ONE v_perm
__device__ __forceinline__ unsigned pack_tr(float a, float b) {
    return __builtin_amdgcn_perm(__float_as_uint(b), __float_as_uint(a), 0x07060302u);
}
__device__ __forceinline__ float fast_sigmoid(float x) {
    return __builtin_amdgcn_rcpf(1.f + __expf(-x));
}
__device__ __forceinline__ void dma16(const void* g, void* l) {
    __builtin_amdgcn_global_load_lds((const __attribute__((address_space(1))) unsigned int*)g,
                                     (__attribute__((address_space(3))) unsigned int*)l, 16, 0, 0);
}
__device__ __forceinline__ void dma4(const void* g, void* l) {
    __builtin_amdgcn_global_load_lds((const __attribute__((address_space(1))) unsigned int*)g,
                                     (__attribute__((address_space(3))) unsigned int*)l, 4, 0, 0);
}

// K0: W_u fp32 -> bf16 row-major (RTNE)
__global__ void k_convert(const float* __restrict__ W, unsigned short* __restrict__ Wb, int n) {
    int i = blockIdx.x * 256 + threadIdx.x;
    if (i < n) Wb[i] = f2bf(W[i]);
}

// K1: feat_v[b] = feat[last_nodes[b]] @ W_v.T + b_v
__global__ __launch_bounds__(256) void k_featv(
    const float* __restrict__ feat, const int* __restrict__ last_nodes,
    const float* __restrict__ Wv, const float* __restrict__ bv,
    float* __restrict__ featv, int Bseg) {
    __shared__ float fln[G][D];
    const int t  = threadIdx.x;
    const int b0 = blockIdx.x * G;
    for (int g = 0; g < G; ++g) {
        int b = b0 + g;
        int ln = (b < Bseg) ? last_nodes[b] : 0;
        fln[g][t] = feat[(long)ln * D + t];
    }
    __syncthreads();
    float acc[G];
    float bvj = bv[t];
    #pragma unroll
    for (int g = 0; g < G; ++g) acc[g] = bvj;
    const float* wr = Wv + (long)t * D;
    for (int k = 0; k < D; k += 4) {
        float4 w4 = *(const float4*)(wr + k);
        #pragma unroll
        for (int g = 0; g < G; ++g) {
            acc[g] += w4.x * fln[g][k]     + w4.y * fln[g][k + 1]
                    + w4.z * fln[g][k + 2] + w4.w * fln[g][k + 3];
        }
    }
    for (int g = 0; g < G; ++g)
        if (b0 + g < Bseg) featv[(long)(b0 + g) * D + t] = acc[g];
}

// K2: persistent, DMA-double-buffered fused kernel.
__global__ __launch_bounds__(512, 2) void k_main(
    const float* __restrict__ feat, const float* __restrict__ cnt,
    const int* __restrict__ seg, const unsigned short* __restrict__ Wub,
    const float* __restrict__ featv, const float* __restrict__ we,
    float* __restrict__ rst, int N) {

    __shared__ float A[2][MT][D];          // 128 KB, XOR-swizzled granules
    __shared__ int   seg_all[CMAX * MT];   // 8 KB
    __shared__ float cnt_all[CMAX * MT];   // 8 KB
    __shared__ float e_s[NW][MT];          // 2 KB
    __shared__ float alpha_s[MT];

    const int t  = threadIdx.x;
    const int w  = t >> 6;
    const int l  = t & 63;
    const int rl = l & 15;
    const int h  = l >> 4;

    const int T   = (N + MT - 1) / MT;
    const int nb  = gridDim.x;
    const int per = T / nb, rem = T % nb;
    const int bid = blockIdx.x;
    const int c0  = bid * per + (bid < rem ? bid : rem);
    const int c1  = c0 + per + (bid < rem ? 1 : 0);
    if (c0 >= c1) return;
    const int ntile = c1 - c0;             // <= CMAX by grid sizing

    // W_u fragments resident in registers: rows [32w, 32w+32), all K
    short8 a_reg[2][8];
    {
        const unsigned short* ab = Wub + (long)(32 * w + rl) * D + h * 8;
        #pragma unroll
        for (int mt = 0; mt < 2; ++mt)
            #pragma unroll
            for (int s = 0; s < 8; ++s)
                a_reg[mt][s] = *(const short8*)(ab + (long)mt * 16 * D + s * 32);
    }
    f32x4 wev[2];
    wev[0] = *(const f32x4*)(we + 32 * w + h * 4);
    wev[1] = *(const f32x4*)(we + 32 * w + 16 + h * 4);

    // prologue: stage all seg/cnt for this block's chunk + feat tile c0 -> buf 0
    {
        const long base = (long)c0 * MT;
        for (int k = w; k < ntile; k += NW) {
            long idx = base + (long)k * MT + l;
            if (idx > (long)N - 1) idx = (long)N - 1;
            dma4(seg + idx, &seg_all[k * MT]);
            dma4(cnt + idx, &cnt_all[k * MT]);
        }
        const long m0 = (long)c0 * MT;
        #pragma unroll
        for (int k = 0; k < 8; ++k) {
            int r = (w << 3) + k;              // r & 7 == k
            long rn = m0 + r; if (rn > (long)N - 1) rn = (long)N - 1;
            dma16(feat + rn * D + ((l ^ k) << 2), &A[0][r][0]);
        }
    }
    asm volatile("s_waitcnt vmcnt(0) lgkmcnt(0)\ns_barrier" ::: "memory");

    int b = 0;
    for (int tt = c0; tt < c1; ++tt, b ^= 1) {
        const int n0  = tt * MT;
        const int nv  = min(MT, N - n0);
        const int rel = tt - c0;
        const int* seg_t = &seg_all[rel * MT];
        const bool more = (tt + 1 < c1);

        // segment ids for this tile's node groups
        int sgv[4];
        #pragma unroll
        for (int nt = 0; nt < 4; ++nt) sgv[nt] = seg_t[nt * 16 + rl];

        // featv loads FIRST (older than the DMA -> counted vmcnt waits later)
        f32x4 fvr[2][4];
        #pragma unroll
        for (int nt = 0; nt < 4; ++nt) {
            const float* fb = featv + (long)sgv[nt] * D + 32 * w + h * 4;
            fvr[0][nt] = *(const f32x4*)(fb);
            fvr[1][nt] = *(const f32x4*)(fb + 16);
        }
        asm volatile("" ::: "memory");
        if (more) {
            const long m0 = (long)(tt + 1) * MT;
            const int bn = b ^ 1;
            #pragma unroll
            for (int k = 0; k < 8; ++k) {
                int r = (w << 3) + k;
                long rn = m0 + r; if (rn > (long)N - 1) rn = (long)N - 1;
                dma16(feat + rn * D + ((l ^ k) << 2), &A[bn][r][0]);
            }
        }
        asm volatile("" ::: "memory");

        // MFMA: u[j][node], A-frags from regs, B-frags from swizzled fp32 LDS
        f32x4 acc[2][4];
        #pragma unroll
        for (int mt = 0; mt < 2; ++mt)
            #pragma unroll
            for (int nt = 0; nt < 4; ++nt) acc[mt][nt] = (f32x4)0.f;

        const float* Ab = &A[b][0][0];
        #pragma unroll
        for (int s = 0; s < 8; ++s) {
            short8 bf[4];
            #pragma unroll
            for (int nt = 0; nt < 4; ++nt) {
                const int row = nt * 16 + rl;
                const int key = row & 7;
                const int g0  = s * 8 + h * 2;
                f32x4 lo = *(const f32x4*)(Ab + row * D + ((g0 ^ key) << 2));
                f32x4 hi = *(const f32x4*)(Ab + row * D + (((g0 + 1) ^ key) << 2));
                union { unsigned u[4]; short8 s8; } cv;
                cv.u[0] = pack_tr(lo[0], lo[1]);
                cv.u[1] = pack_tr(lo[2], lo[3]);
                cv.u[2] = pack_tr(hi[0], hi[1]);
                cv.u[3] = pack_tr(hi[2], hi[3]);
                bf[nt] = cv.s8;
            }
            #pragma unroll
            for (int mt = 0; mt < 2; ++mt)
                #pragma unroll
                for (int nt = 0; nt < 4; ++nt)
                    acc[mt][nt] = __builtin_amdgcn_mfma_f32_16x16x32_bf16(a_reg[mt][s], bf[nt], acc[mt][nt], 0, 0, 0);
        }

        // epilogue: e partials; lane's j = 32w + 16mt + 4h + r, node = 16nt + rl
        float ep[4] = {0.f, 0.f, 0.f, 0.f};
        #pragma unroll
        for (int mt = 0; mt < 2; ++mt) {
            #pragma unroll
            for (int nt = 0; nt < 4; ++nt) {
                #pragma unroll
                for (int r = 0; r < 4; ++r)
                    ep[nt] += wev[mt][r] * fast_sigmoid(acc[mt][nt][r] + fvr[mt][nt][r]);
            }
        }
        #pragma unroll
        for (int nt = 0; nt < 4; ++nt) {
            ep[nt] += __shfl_xor(ep[nt], 16);
            ep[nt] += __shfl_xor(ep[nt], 32);
        }
        if (h == 0) {
            #pragma unroll
            for (int nt = 0; nt < 4; ++nt) e_s[w][nt * 16 + rl] = ep[nt];
        }
        asm volatile("s_waitcnt lgkmcnt(0)\ns_barrier" ::: "memory");

        if (t < MT) {
            float e = 0.f;
            #pragma unroll
            for (int q = 0; q < NW; ++q) e += e_s[q][t];
            alpha_s[t] = e * cnt_all[rel * MT + t];
        }
        asm volatile("s_waitcnt lgkmcnt(0)\ns_barrier" ::: "memory");

        // segment-sum from fp32 LDS tile; thread (half, d) does 32 rows of dim d
        {
            const int half = t >> 8;
            const int d    = t & 255;
            const int i0   = half * 32;
            const int i1   = min(i0 + 32, nv);
            if (i0 < i1) {
                const int dg = d >> 2, db = d & 3;
                if ((seg_t[i0] == seg_t[i1 - 1]) && (i1 - i0) == 32) {
                    float c0a = 0.f, c1a = 0.f, c2a = 0.f, c3a = 0.f;
                    #pragma unroll
                    for (int i = i0; i < i0 + 32; i += 4) {
                        c0a += Ab[(i + 0) * D + ((dg ^ ((i + 0) & 7)) << 2) + db] * alpha_s[i + 0];
                        c1a += Ab[(i + 1) * D + ((dg ^ ((i + 1) & 7)) << 2) + db] * alpha_s[i + 1];
                        c2a += Ab[(i + 2) * D + ((dg ^ ((i + 2) & 7)) << 2) + db] * alpha_s[i + 2];
                        c3a += Ab[(i + 3) * D + ((dg ^ ((i + 3) & 7)) << 2) + db] * alpha_s[i + 3];
                    }
                    atomicAdd(&rst[(long)seg_t[i0] * D + d], (c0a + c1a) + (c2a + c3a));
                } else {
                    float c = 0.f;
                    int cur = seg_t[i0];
                    for (int i = i0; i < i1; ++i) {
                        int sgi = seg_t[i];
                        if (sgi != cur) { atomicAdd(&rst[(long)cur * D + d], c); c = 0.f; cur = sgi; }
                        c += Ab[i * D + ((dg ^ (i & 7)) << 2) + db] * alpha_s[i];
                    }
                    atomicAdd(&rst[(long)cur * D + d], c);
                }
            }
        }
        // full drain: prefetched tile landed, atomics retired
        asm volatile("s_waitcnt vmcnt(0) lgkmcnt(0)\ns_barrier" ::: "memory");
    }
}

extern "C" void kernel_launch(void* const* d_in, const int* in_sizes, int n_in,
                              void* d_out, int out_size, void* d_ws, size_t ws_size,
                              hipStream_t stream) {
    const float* feat = (const float*)d_in[0];
    const float* cnt  = (const float*)d_in[1];
    const int*   segp = (const int*)d_in[2];
    const int*   last = (const int*)d_in[3];
    const float* Wu   = (const float*)d_in[4];
    const float* Wv   = (const float*)d_in[5];
    const float* bv   = (const float*)d_in[6];
    const float* we   = (const float*)d_in[7];
    float* rst = (float*)d_out;

    const int N    = in_sizes[1];
    const int Bseg = in_sizes[3];

    unsigned short* Wub   = (unsigned short*)d_ws;
    float*          featv = (float*)((char*)d_ws + (size_t)D * D * sizeof(unsigned short));

    const int T = (N + MT - 1) / MT;
    int grid = GRID_MAIN;
    while ((T + grid - 1) / grid > CMAX) grid *= 2;   // keep tiles/block <= CMAX

    hipMemsetAsync(d_out, 0, (size_t)out_size * sizeof(float), stream);
    k_convert<<<(D * D + 255) / 256, 256, 0, stream>>>(Wu, Wub, D * D);
    k_featv<<<(Bseg + G - 1) / G, 256, 0, stream>>>(feat, last, Wv, bv, featv, Bseg);
    k_main<<<grid, 512, 0, stream>>>(feat, cnt, segp, Wub, featv, we, rst, N);
}

// Round 4
// 198.972 us; speedup vs baseline: 3.1549x; 1.1905x over previous
//
#include <hip/hip_runtime.h>
#include <hip/hip_bf16.h>

typedef __attribute__((ext_vector_type(8))) short short8;
typedef __attribute__((ext_vector_type(4))) float f32x4;

#define D 256
#define MT 64
#define NW 8              // waves per block (512 threads)
#define GRID_MAIN 256
#define G 8

__device__ __forceinline__ unsigned short f2bf(float f) {
    unsigned int u = __float_as_uint(f);
    u += 0x7FFFu + ((u >> 16) & 1u);   // RTNE
    return (unsigned short)(u >> 16);
}
__device__ __forceinline__ unsigned pack2(float a, float b) {
    return (unsigned)f2bf(a) | ((unsigned)f2bf(b) << 16);
}
__device__ __forceinline__ float bf2f(unsigned short s) {
    return __uint_as_float(((unsigned int)s) << 16);
}
__device__ __forceinline__ float fast_sigmoid(float x) {
    return __builtin_amdgcn_rcpf(1.f + __expf(-x));
}

// K0: W_u fp32 -> bf16 row-major (RTNE)
__global__ void k_convert(const float* __restrict__ W, unsigned short* __restrict__ Wb, int n) {
    int i = blockIdx.x * 256 + threadIdx.x;
    if (i < n) Wb[i] = f2bf(W[i]);
}

// K1: feat_v[b] = feat[last_nodes[b]] @ W_v.T + b_v
__global__ __launch_bounds__(256) void k_featv(
    const float* __restrict__ feat, const int* __restrict__ last_nodes,
    const float* __restrict__ Wv, const float* __restrict__ bv,
    float* __restrict__ featv, int Bseg) {
    __shared__ float fln[G][D];
    const int t  = threadIdx.x;
    const int b0 = blockIdx.x * G;
    for (int g = 0; g < G; ++g) {
        int b = b0 + g;
        int ln = (b < Bseg) ? last_nodes[b] : 0;
        fln[g][t] = feat[(long)ln * D + t];
    }
    __syncthreads();
    float acc[G];
    float bvj = bv[t];
    #pragma unroll
    for (int g = 0; g < G; ++g) acc[g] = bvj;
    const float* wr = Wv + (long)t * D;
    for (int k = 0; k < D; k += 4) {
        float4 w4 = *(const float4*)(wr + k);
        #pragma unroll
        for (int g = 0; g < G; ++g) {
            acc[g] += w4.x * fln[g][k]     + w4.y * fln[g][k + 1]
                    + w4.z * fln[g][k + 2] + w4.w * fln[g][k + 3];
        }
    }
    for (int g = 0; g < G; ++g)
        if (b0 + g < Bseg) featv[(long)(b0 + g) * D + t] = acc[g];
}

// K2: persistent fused kernel, bf16 XOR-swizzled LDS tile, reg-staged.
// LDS layout: tile row r (512 B), 16B-granule g stored at granule (g ^ (r&7)).
__global__ __launch_bounds__(512, 2) void k_main(
    const float* __restrict__ feat, const float* __restrict__ cnt,
    const int* __restrict__ seg, const unsigned short* __restrict__ Wub,
    const float* __restrict__ featv, const float* __restrict__ we,
    float* __restrict__ rst, int N) {

    __shared__ unsigned short Abuf[2][MT][D];   // 64 KB
    __shared__ float e_s[NW][MT];               // 2 KB
    __shared__ int   seg_s[2][MT];
    __shared__ float cnt_s[2][MT];
    __shared__ float alpha_s[MT];

    const int t  = threadIdx.x;
    const int w  = t >> 6;
    const int l  = t & 63;
    const int rl = l & 15;
    const int h  = l >> 4;

    const int T   = (N + MT - 1) / MT;
    const int nb  = gridDim.x;
    const int per = T / nb, rem = T % nb;
    const int bid = blockIdx.x;
    const int c0  = bid * per + (bid < rem ? bid : rem);
    const int c1  = c0 + per + (bid < rem ? 1 : 0);
    if (c0 >= c1) return;

    // W_u rows [32w, 32w+32) resident in registers
    short8 a_reg[2][8];
    {
        const unsigned short* ab = Wub + (long)(32 * w + rl) * D + h * 8;
        #pragma unroll
        for (int mt = 0; mt < 2; ++mt)
            #pragma unroll
            for (int s = 0; s < 8; ++s)
                a_reg[mt][s] = *(const short8*)(ab + (long)mt * 16 * D + s * 32);
    }
    f32x4 wev[2];
    wev[0] = *(const f32x4*)(we + 32 * w + h * 4);
    wev[1] = *(const f32x4*)(we + 32 * w + 16 + h * 4);

    // ---- prologue: stage tile c0 into buf 0 ----
    {
        const long m0 = (long)c0 * MT;
        float4 sv[8];
        #pragma unroll
        for (int k = 0; k < 8; ++k) {
            long n = m0 + w * 8 + k; if (n > (long)N - 1) n = (long)N - 1;
            sv[k] = *(const float4*)(feat + n * D + 4 * l);
        }
        int sr = 0; float cr = 0.f;
        if (t < MT) {
            long n = m0 + t;
            if (n < N) { sr = seg[n]; cr = cnt[n]; }
            else       { sr = seg[N - 1]; cr = 0.f; }
        }
        #pragma unroll
        for (int k = 0; k < 8; ++k) {
            int R = w * 8 + k;                       // R & 7 == k
            uint2 v = make_uint2(pack2(sv[k].x, sv[k].y), pack2(sv[k].z, sv[k].w));
            *(uint2*)&Abuf[0][R][(((l >> 1) ^ k) << 3) + (l & 1) * 4] = v;
        }
        if (t < MT) { seg_s[0][t] = sr; cnt_s[0][t] = cr; }
        __syncthreads();
    }

    int cur = 0;
    for (int tt = c0; tt < c1; ++tt, cur ^= 1) {
        const int n0  = tt * MT;
        const int nv  = min(MT, N - n0);
        const bool more = (tt + 1 < c1);
        const int* seg_t = seg_s[cur];

        // segment ids for this tile's node groups
        int sgv[4];
        #pragma unroll
        for (int nt = 0; nt < 4; ++nt) sgv[nt] = seg_t[nt * 16 + rl];

        // featv loads FIRST (oldest vmem -> counted waits later)
        f32x4 fvr[2][4];
        #pragma unroll
        for (int nt = 0; nt < 4; ++nt) {
            const float* fb = featv + (long)sgv[nt] * D + 32 * w + h * 4;
            fvr[0][nt] = *(const f32x4*)(fb);
            fvr[1][nt] = *(const f32x4*)(fb + 16);
        }
        asm volatile("" ::: "memory");

        // stage loads for tile t+1 (held in regs until after P-alpha barrier)
        float4 sv[8];
        int sr = 0; float cr = 0.f;
        if (more) {
            const long m1 = (long)(tt + 1) * MT;
            #pragma unroll
            for (int k = 0; k < 8; ++k) {
                long n = m1 + w * 8 + k; if (n > (long)N - 1) n = (long)N - 1;
                sv[k] = *(const float4*)(feat + n * D + 4 * l);
            }
            if (t < MT) {
                long n = m1 + t;
                if (n < N) { sr = seg[n]; cr = cnt[n]; }
                else       { sr = seg[N - 1]; cr = 0.f; }
            }
        }
        asm volatile("" ::: "memory");

        // MFMA: u[j][node]; A from regs, B from bf16 swizzled LDS
        f32x4 acc[2][4];
        #pragma unroll
        for (int mt = 0; mt < 2; ++mt)
            #pragma unroll
            for (int nt = 0; nt < 4; ++nt) acc[mt][nt] = (f32x4)0.f;

        const unsigned short* Ab = &Abuf[cur][0][0];
        #pragma unroll
        for (int s = 0; s < 8; ++s) {
            short8 bfr[4];
            #pragma unroll
            for (int nt = 0; nt < 4; ++nt) {
                int R = nt * 16 + rl;
                int gr = (s * 4 + h) ^ (rl & 7);
                bfr[nt] = *(const short8*)(Ab + R * D + gr * 8);
            }
            #pragma unroll
            for (int mt = 0; mt < 2; ++mt)
                #pragma unroll
                for (int nt = 0; nt < 4; ++nt)
                    acc[mt][nt] = __builtin_amdgcn_mfma_f32_16x16x32_bf16(a_reg[mt][s], bfr[nt], acc[mt][nt], 0, 0, 0);
        }

        // epilogue: e partials; lane's j = 32w + 16mt + 4h + r, node = 16nt + rl
        float ep[4] = {0.f, 0.f, 0.f, 0.f};
        #pragma unroll
        for (int mt = 0; mt < 2; ++mt)
            #pragma unroll
            for (int nt = 0; nt < 4; ++nt)
                #pragma unroll
                for (int r = 0; r < 4; ++r)
                    ep[nt] += wev[mt][r] * fast_sigmoid(acc[mt][nt][r] + fvr[mt][nt][r]);
        #pragma unroll
        for (int nt = 0; nt < 4; ++nt) {
            ep[nt] += __shfl_xor(ep[nt], 16);
            ep[nt] += __shfl_xor(ep[nt], 32);
        }
        if (h == 0) {
            #pragma unroll
            for (int nt = 0; nt < 4; ++nt) e_s[w][nt * 16 + rl] = ep[nt];
        }
        asm volatile("s_waitcnt lgkmcnt(0)\ns_barrier" ::: "memory");   // barrier 1

        if (t < MT) {
            float e = 0.f;
            #pragma unroll
            for (int q = 0; q < NW; ++q) e += e_s[q][t];
            alpha_s[t] = e * cnt_s[cur][t];
        }
        asm volatile("s_waitcnt lgkmcnt(0)\ns_barrier" ::: "memory");   // barrier 2

        // write staged tile t+1 into buf^1 (vmcnt wait is counted: atomics are newer)
        if (more) {
            #pragma unroll
            for (int k = 0; k < 8; ++k) {
                int R = w * 8 + k;
                uint2 v = make_uint2(pack2(sv[k].x, sv[k].y), pack2(sv[k].z, sv[k].w));
                *(uint2*)&Abuf[cur ^ 1][R][(((l >> 1) ^ k) << 3) + (l & 1) * 4] = v;
            }
            if (t < MT) { seg_s[cur ^ 1][t] = sr; cnt_s[cur ^ 1][t] = cr; }
        }

        // P4: segment-sum readout from bf16 tile; thread (half,d): 32 rows of dim d
        {
            const int halfq = t >> 8;
            const int d     = t & 255;
            const int i0    = halfq * 32;
            const int i1v   = min(i0 + 32, nv);
            const int dg = d >> 3, db = d & 7;
            if (i0 < i1v) {
                if ((i1v - i0) == 32 && seg_t[i0] == seg_t[i1v - 1]) {
                    float c0a = 0.f, c1a = 0.f, c2a = 0.f, c3a = 0.f;
                    #pragma unroll
                    for (int i2 = 0; i2 < 32; i2 += 4) {
                        int i = i0 + i2;
                        c0a += bf2f(Ab[(i + 0) * D + (((dg ^ ((i + 0) & 7))) << 3) + db]) * alpha_s[i + 0];
                        c1a += bf2f(Ab[(i + 1) * D + (((dg ^ ((i + 1) & 7))) << 3) + db]) * alpha_s[i + 1];
                        c2a += bf2f(Ab[(i + 2) * D + (((dg ^ ((i + 2) & 7))) << 3) + db]) * alpha_s[i + 2];
                        c3a += bf2f(Ab[(i + 3) * D + (((dg ^ ((i + 3) & 7))) << 3) + db]) * alpha_s[i + 3];
                    }
                    atomicAdd(&rst[(long)seg_t[i0] * D + d], (c0a + c1a) + (c2a + c3a));
                } else {
                    float c = 0.f;
                    int curseg = seg_t[i0];
                    for (int i = i0; i < i1v; ++i) {
                        int sgi = seg_t[i];
                        if (sgi != curseg) { atomicAdd(&rst[(long)curseg * D + d], c); c = 0.f; curseg = sgi; }
                        c += bf2f(Ab[i * D + ((dg ^ (i & 7)) << 3) + db]) * alpha_s[i];
                    }
                    atomicAdd(&rst[(long)curseg * D + d], c);
                }
            }
        }
        asm volatile("s_waitcnt lgkmcnt(0)\ns_barrier" ::: "memory");   // barrier 3
    }
}

extern "C" void kernel_launch(void* const* d_in, const int* in_sizes, int n_in,
                              void* d_out, int out_size, void* d_ws, size_t ws_size,
                              hipStream_t stream) {
    const float* feat = (const float*)d_in[0];
    const float* cnt  = (const float*)d_in[1];
    const int*   segp = (const int*)d_in[2];
    const int*   last = (const int*)d_in[3];
    const float* Wu   = (const float*)d_in[4];
    const float* Wv   = (const float*)d_in[5];
    const float* bv   = (const float*)d_in[6];
    const float* we   = (const float*)d_in[7];
    float* rst = (float*)d_out;

    const int N    = in_sizes[1];
    const int Bseg = in_sizes[3];

    unsigned short* Wub   = (unsigned short*)d_ws;
    float*          featv = (float*)((char*)d_ws + (size_t)D * D * sizeof(unsigned short));

    hipMemsetAsync(d_out, 0, (size_t)out_size * sizeof(float), stream);
    k_convert<<<(D * D + 255) / 256, 256, 0, stream>>>(Wu, Wub, D * D);
    k_featv<<<(Bseg + G - 1) / G, 256, 0, stream>>>(feat, last, Wv, bv, featv, Bseg);
    k_main<<<GRID_MAIN, 512, 0, stream>>>(feat, cnt, segp, Wub, featv, we, rst, N);
}